// Round 1
// baseline (7689.857 us; speedup 1.0000x reference)
//
#include <hip/hip_runtime.h>

#define NU 200000
#define NR 50000
#define DD 64
#define NE 2000000
#define NQ 500000

// -------------------- degree count --------------------
__global__ void count_kernel(const int* __restrict__ dst, float* __restrict__ cnt, int n) {
    int i = blockIdx.x * blockDim.x + threadIdx.x;
    if (i < n) atomicAdd(&cnt[dst[i]], 1.0f);
}

// -------------------- scatter-add aggregation --------------------
// one thread per (edge, feature); 64 consecutive threads share an edge
__global__ void scatter_add_kernel(const float* __restrict__ h,
                                   const int* __restrict__ src,
                                   const int* __restrict__ dst,
                                   float* __restrict__ agg) {
    long long idx = (long long)blockIdx.x * blockDim.x + threadIdx.x;
    if (idx >= (long long)NE * DD) return;
    int e = (int)(idx >> 6);
    int f = (int)(idx & 63);
    int s = src[e], d = dst[e];
    atomicAdd(&agg[(long long)d * DD + f], h[(long long)s * DD + f]);
}

// -------------------- SAGE linear: out = relu?( (agg/cnt)@Wl^T + bl + h@Wr^T ) ----
__global__ __launch_bounds__(256)
void linear_kernel(const float* __restrict__ agg, const float* __restrict__ cnt,
                   const float* __restrict__ h,
                   const float* __restrict__ Wl, const float* __restrict__ Wr,
                   const float* __restrict__ bias,
                   float* __restrict__ out, int n, int do_relu) {
    __shared__ float WlT[DD * DD];   // [k][c] layout: lane c -> bank c%32, 2-way free
    __shared__ float WrT[DD * DD];
    __shared__ float b_s[DD];
    for (int i = threadIdx.x; i < DD * DD; i += 256) {
        int c = i >> 6, k = i & 63;
        WlT[k * DD + c] = Wl[i];     // W[c,k] -> WT[k,c]
        WrT[k * DD + c] = Wr[i];
    }
    if (threadIdx.x < DD) b_s[threadIdx.x] = bias[threadIdx.x];
    __syncthreads();

    int lane = threadIdx.x & 63;
    int wave = blockIdx.x * 4 + (threadIdx.x >> 6);
    int nwaves = gridDim.x * 4;
    for (int r = wave; r < n; r += nwaves) {
        float rc = 1.0f / fmaxf(cnt[r], 1.0f);
        float mv = agg[(long long)r * DD + lane] * rc;
        float hv = h[(long long)r * DD + lane];
        float acc = b_s[lane];
#pragma unroll
        for (int k = 0; k < DD; k++) {
            acc += __shfl(mv, k) * WlT[k * DD + lane];
            acc += __shfl(hv, k) * WrT[k * DD + lane];
        }
        if (do_relu) acc = fmaxf(acc, 0.0f);
        out[(long long)r * DD + lane] = acc;
    }
}

// -------------------- fused edge decoder --------------------
__global__ __launch_bounds__(256)
void decoder_kernel(const float* __restrict__ hu, const float* __restrict__ hr,
                    const int* __restrict__ el_row, const int* __restrict__ el_col,
                    const float* __restrict__ dW1, const float* __restrict__ db1,
                    const float* __restrict__ dW2, const float* __restrict__ db2,
                    const float* __restrict__ dW3, const float* __restrict__ db3,
                    float* __restrict__ out) {
    __shared__ float W1T[2 * DD * DD];  // [k][c], k in 0..127
    __shared__ float W2T[DD * DD];
    __shared__ float W3s[DD];
    __shared__ float b1s[DD], b2s[DD];
    for (int i = threadIdx.x; i < 2 * DD * DD; i += 256) {
        int c = i >> 7, k = i & 127;    // dW1[c,k] at c*128+k
        W1T[k * DD + c] = dW1[i];
    }
    for (int i = threadIdx.x; i < DD * DD; i += 256) {
        int c = i >> 6, k = i & 63;
        W2T[k * DD + c] = dW2[i];
    }
    if (threadIdx.x < DD) {
        W3s[threadIdx.x] = dW3[threadIdx.x];
        b1s[threadIdx.x] = db1[threadIdx.x];
        b2s[threadIdx.x] = db2[threadIdx.x];
    }
    __syncthreads();
    float b3 = db3[0];

    int lane = threadIdx.x & 63;
    int wave = blockIdx.x * 4 + (threadIdx.x >> 6);
    int nwaves = gridDim.x * 4;
    for (int q = wave; q < NQ; q += nwaves) {
        int row = el_row[q], col = el_col[q];
        float uv = hu[(long long)row * DD + lane];
        float rv = hr[(long long)col * DD + lane];
        float acc = b1s[lane];
#pragma unroll
        for (int k = 0; k < DD; k++) acc += __shfl(uv, k) * W1T[k * DD + lane];
#pragma unroll
        for (int k = 0; k < DD; k++) acc += __shfl(rv, k) * W1T[(DD + k) * DD + lane];
        float z1 = fmaxf(acc, 0.0f);
        float acc2 = b2s[lane];
#pragma unroll
        for (int k = 0; k < DD; k++) acc2 += __shfl(z1, k) * W2T[k * DD + lane];
        float z2 = fmaxf(acc2, 0.0f);
        float p = z2 * W3s[lane];
#pragma unroll
        for (int off = 32; off > 0; off >>= 1) p += __shfl_down(p, off);
        if (lane == 0) out[q] = p + b3;
    }
}

extern "C" void kernel_launch(void* const* d_in, const int* in_sizes, int n_in,
                              void* d_out, int out_size, void* d_ws, size_t ws_size,
                              hipStream_t stream) {
    const float* x_user = (const float*)d_in[0];
    const float* x_rest = (const float*)d_in[1];
    const float* Wl     = (const float*)d_in[2];   // [3,2,64,64]
    const float* Wr     = (const float*)d_in[3];
    const float* bl     = (const float*)d_in[4];   // [3,2,64]
    const float* dW1    = (const float*)d_in[5];
    const float* db1    = (const float*)d_in[6];
    const float* dW2    = (const float*)d_in[7];
    const float* db2    = (const float*)d_in[8];
    const float* dW3    = (const float*)d_in[9];
    const float* db3    = (const float*)d_in[10];
    const int* ur_src   = (const int*)d_in[11];
    const int* ur_dst   = (const int*)d_in[12];
    const int* ru_src   = (const int*)d_in[13];
    const int* ru_dst   = (const int*)d_in[14];
    const int* el_row   = (const int*)d_in[15];
    const int* el_col   = (const int*)d_in[16];
    float* out = (float*)d_out;

    char* w = (char*)d_ws;
    size_t off = 0;
    auto alloc = [&](size_t n) -> float* { float* p = (float*)(w + off); off += n * 4; return p; };
    float* hu0   = alloc((size_t)NU * DD);
    float* hu1   = alloc((size_t)NU * DD);
    float* hr0   = alloc((size_t)NR * DD);
    float* hr1   = alloc((size_t)NR * DD);
    float* agg_u = alloc((size_t)NU * DD);
    float* agg_r = alloc((size_t)NR * DD);
    float* cnt_u = alloc(NU);
    float* cnt_r = alloc(NR);

    // degrees (layer-independent)
    hipMemsetAsync(cnt_u, 0, (size_t)NU * 4, stream);
    hipMemsetAsync(cnt_r, 0, (size_t)NR * 4, stream);
    count_kernel<<<(NE + 255) / 256, 256, 0, stream>>>(ur_dst, cnt_r, NE);
    count_kernel<<<(NE + 255) / 256, 256, 0, stream>>>(ru_dst, cnt_u, NE);

    const float* cu = x_user;
    const float* cr = x_rest;
    float* nu_[3] = {hu0, hu1, hu0};
    float* nr_[3] = {hr0, hr1, hr0};
    unsigned sgrid = (unsigned)(((long long)NE * DD + 255) / 256);

    for (int l = 0; l < 3; l++) {
        // restaurant side: aggregate users over ur edges
        hipMemsetAsync(agg_r, 0, (size_t)NR * DD * 4, stream);
        scatter_add_kernel<<<sgrid, 256, 0, stream>>>(cu, ur_src, ur_dst, agg_r);
        // user side: aggregate restaurants over ru edges
        hipMemsetAsync(agg_u, 0, (size_t)NU * DD * 4, stream);
        scatter_add_kernel<<<sgrid, 256, 0, stream>>>(cr, ru_src, ru_dst, agg_u);

        const float* Wl_r = Wl + (size_t)(l * 2 + 0) * DD * DD;
        const float* Wr_r = Wr + (size_t)(l * 2 + 0) * DD * DD;
        const float* bl_r = bl + (size_t)(l * 2 + 0) * DD;
        const float* Wl_u = Wl + (size_t)(l * 2 + 1) * DD * DD;
        const float* Wr_u = Wr + (size_t)(l * 2 + 1) * DD * DD;
        const float* bl_u = bl + (size_t)(l * 2 + 1) * DD;

        linear_kernel<<<1024, 256, 0, stream>>>(agg_r, cnt_r, cr, Wl_r, Wr_r, bl_r, nr_[l], NR, l < 2 ? 1 : 0);
        linear_kernel<<<2048, 256, 0, stream>>>(agg_u, cnt_u, cu, Wl_u, Wr_u, bl_u, nu_[l], NU, l < 2 ? 1 : 0);

        cu = nu_[l];
        cr = nr_[l];
    }

    decoder_kernel<<<2048, 256, 0, stream>>>(cu, cr, el_row, el_col,
                                             dW1, db1, dW2, db2, dW3, db3, out);
}

// Round 2
// 4268.068 us; speedup vs baseline: 1.8017x; 1.8017x over previous
//
#include <hip/hip_runtime.h>

#define NU 200000
#define NR 50000
#define DD 64
#define NE 2000000
#define NQ 500000
#define SCAN_ITEMS 1024

// -------------------- degree count (int) --------------------
__global__ void count_int_kernel(const int* __restrict__ dst, int* __restrict__ cnt, int n) {
    int i = blockIdx.x * blockDim.x + threadIdx.x;
    if (i < n) atomicAdd(&cnt[dst[i]], 1);
}

// -------------------- scan: per-block reduce --------------------
__global__ void scan_reduce_kernel(const int* __restrict__ cnt, int* __restrict__ bsum, int n) {
    __shared__ int s[256];
    int base = blockIdx.x * SCAN_ITEMS;
    int t = 0;
    for (int i = threadIdx.x; i < SCAN_ITEMS; i += 256) {
        int g = base + i;
        t += (g < n) ? cnt[g] : 0;
    }
    s[threadIdx.x] = t;
    __syncthreads();
    for (int off = 128; off > 0; off >>= 1) {
        if (threadIdx.x < off) s[threadIdx.x] += s[threadIdx.x + off];
        __syncthreads();
    }
    if (threadIdx.x == 0) bsum[blockIdx.x] = s[0];
}

// -------------------- scan: single-block exclusive scan of block sums ------
__global__ void scan_bsum_kernel(int* __restrict__ bsum, int nb) {
    __shared__ int a[256], b[256];
    int tid = threadIdx.x;
    a[tid] = (tid < nb) ? bsum[tid] : 0;
    __syncthreads();
    int* cur = a; int* alt = b;
    for (int off = 1; off < 256; off <<= 1) {
        int t = cur[tid];
        if (tid >= off) t += cur[tid - off];
        alt[tid] = t;
        __syncthreads();
        int* tmp = cur; cur = alt; alt = tmp;
    }
    int excl = (tid == 0) ? 0 : cur[tid - 1];
    if (tid < nb) bsum[tid] = excl;
}

// -------------------- scan: write exclusive row starts --------------------
__global__ void scan_write_kernel(const int* __restrict__ cnt, const int* __restrict__ bsum,
                                  int* __restrict__ rs, int n, int total) {
    __shared__ int sa[256], sb[256];
    int tid = threadIdx.x;
    int base = blockIdx.x * SCAN_ITEMS;
    int loc[4];
    int t = 0;
#pragma unroll
    for (int i = 0; i < 4; i++) {
        int g = base + tid * 4 + i;
        int v = (g < n) ? cnt[g] : 0;
        loc[i] = t;
        t += v;
    }
    sa[tid] = t;
    __syncthreads();
    int* cur = sa; int* alt = sb;
    for (int off = 1; off < 256; off <<= 1) {
        int x = cur[tid];
        if (tid >= off) x += cur[tid - off];
        alt[tid] = x;
        __syncthreads();
        int* tmp = cur; cur = alt; alt = tmp;
    }
    int texcl = cur[tid] - t;  // exclusive prefix of this thread
    int off0 = bsum[blockIdx.x] + texcl;
#pragma unroll
    for (int i = 0; i < 4; i++) {
        int g = base + tid * 4 + i;
        if (g < n) rs[g] = off0 + loc[i];
    }
    if (blockIdx.x == 0 && tid == 0) rs[n] = total;
}

// -------------------- CSR fill --------------------
__global__ void fill_csr_kernel(const int* __restrict__ src, const int* __restrict__ dst,
                                const int* __restrict__ rs, int* __restrict__ cursor,
                                int* __restrict__ csr, int n) {
    int e = blockIdx.x * blockDim.x + threadIdx.x;
    if (e < n) {
        int d = dst[e];
        int pos = atomicAdd(&cursor[d], 1);
        csr[rs[d] + pos] = src[e];
    }
}

// -------------------- gather mean: wave per dst row --------------------
__global__ __launch_bounds__(256)
void gather_mean_kernel(const float* __restrict__ h, const int* __restrict__ csr,
                        const int* __restrict__ rs, float* __restrict__ mean, int nrows) {
    int lane = threadIdx.x & 63;
    int wave = blockIdx.x * 4 + (threadIdx.x >> 6);
    if (wave >= nrows) return;
    int r = wave;
    int s = rs[r], e = rs[r + 1];
    float a0 = 0.f, a1 = 0.f, a2 = 0.f, a3 = 0.f;
    for (int j = s; j < e; j += 64) {
        int rem = e - j;
        int nch = rem < 64 ? rem : 64;
        int li = lane < nch ? lane : nch - 1;
        int idx = csr[j + li];  // clamped: all lanes hold a valid id
        for (int kk = 0; kk < nch; kk += 4) {
            int i0 = __shfl(idx, kk);
            int i1 = __shfl(idx, kk + 1);
            int i2 = __shfl(idx, kk + 2);
            int i3 = __shfl(idx, kk + 3);
            float v0 = h[i0 * DD + lane];
            float v1 = h[i1 * DD + lane];
            float v2 = h[i2 * DD + lane];
            float v3 = h[i3 * DD + lane];
            a0 += v0;                              // kk < nch always
            a1 += (kk + 1 < nch) ? v1 : 0.f;
            a2 += (kk + 2 < nch) ? v2 : 0.f;
            a3 += (kk + 3 < nch) ? v3 : 0.f;
        }
    }
    float acc = (a0 + a1) + (a2 + a3);
    float inv = 1.0f / fmaxf((float)(e - s), 1.0f);
    mean[r * DD + lane] = acc * inv;
}

// -------------------- SAGE linear: thread per row, scalar weights ---------
// out[r][c] = bias[c] + sum_k mean[r][k]*Wl[c][k] + sum_k h[r][k]*Wr[c][k]
__global__ __launch_bounds__(256)
void sage_linear_kernel(const float* __restrict__ mean, const float* __restrict__ h,
                        const float* __restrict__ Wl, const float* __restrict__ Wr,
                        const float* __restrict__ bias,
                        float* __restrict__ out, int n, int do_relu) {
    int r = blockIdx.x * 256 + threadIdx.x;
    if (r >= n) return;
    float m[DD], x[DD];
    const float4* mp = (const float4*)(mean + (size_t)r * DD);
    const float4* xp = (const float4*)(h + (size_t)r * DD);
#pragma unroll
    for (int i = 0; i < 16; i++) {
        float4 a = mp[i];
        m[4 * i] = a.x; m[4 * i + 1] = a.y; m[4 * i + 2] = a.z; m[4 * i + 3] = a.w;
        float4 b = xp[i];
        x[4 * i] = b.x; x[4 * i + 1] = b.y; x[4 * i + 2] = b.z; x[4 * i + 3] = b.w;
    }
    float* o = out + (size_t)r * DD;
    for (int c = 0; c < DD; c++) {
        const float* wl = Wl + c * DD;
        const float* wr = Wr + c * DD;
        float a0 = 0.f, a1 = 0.f, a2 = 0.f, a3 = 0.f;
#pragma unroll
        for (int k = 0; k < DD; k += 4) {
            a0 += m[k] * wl[k];
            a1 += m[k + 1] * wl[k + 1];
            a2 += m[k + 2] * wl[k + 2];
            a3 += m[k + 3] * wl[k + 3];
        }
#pragma unroll
        for (int k = 0; k < DD; k += 4) {
            a0 += x[k] * wr[k];
            a1 += x[k + 1] * wr[k + 1];
            a2 += x[k + 2] * wr[k + 2];
            a3 += x[k + 3] * wr[k + 3];
        }
        float acc = (a0 + a1) + (a2 + a3) + bias[c];
        o[c] = do_relu ? fmaxf(acc, 0.f) : acc;
    }
}

// -------------------- decoder layer-1 precompute ---------------------------
// P[r][c] = (add_bias ? db1[c] : 0) + sum_k h[r][k] * dW1[c*128 + koff + k]
__global__ __launch_bounds__(256)
void precompute_kernel(const float* __restrict__ h, const float* __restrict__ dW1,
                       const float* __restrict__ db1, float* __restrict__ P,
                       int n, int koff, int add_bias) {
    int r = blockIdx.x * 256 + threadIdx.x;
    if (r >= n) return;
    float x[DD];
    const float4* xp = (const float4*)(h + (size_t)r * DD);
#pragma unroll
    for (int i = 0; i < 16; i++) {
        float4 b = xp[i];
        x[4 * i] = b.x; x[4 * i + 1] = b.y; x[4 * i + 2] = b.z; x[4 * i + 3] = b.w;
    }
    float* o = P + (size_t)r * DD;
    for (int c = 0; c < DD; c++) {
        const float* w = dW1 + c * 2 * DD + koff;
        float a0 = 0.f, a1 = 0.f, a2 = 0.f, a3 = 0.f;
#pragma unroll
        for (int k = 0; k < DD; k += 4) {
            a0 += x[k] * w[k];
            a1 += x[k + 1] * w[k + 1];
            a2 += x[k + 2] * w[k + 2];
            a3 += x[k + 3] * w[k + 3];
        }
        float acc = (a0 + a1) + (a2 + a3);
        if (add_bias) acc += db1[c];
        o[c] = acc;
    }
}

// -------------------- fused decoder: thread per query ----------------------
__global__ __launch_bounds__(256)
void decoder_kernel(const float* __restrict__ Pu, const float* __restrict__ Pr,
                    const int* __restrict__ el_row, const int* __restrict__ el_col,
                    const float* __restrict__ dW2, const float* __restrict__ db2,
                    const float* __restrict__ dW3, const float* __restrict__ db3,
                    float* __restrict__ out) {
    int q = blockIdx.x * 256 + threadIdx.x;
    if (q >= NQ) return;
    int row = el_row[q], col = el_col[q];
    const float4* pu = (const float4*)(Pu + (size_t)row * DD);
    const float4* pr = (const float4*)(Pr + (size_t)col * DD);
    float z1[DD];
#pragma unroll
    for (int i = 0; i < 16; i++) {
        float4 a = pu[i];
        float4 b = pr[i];
        z1[4 * i]     = fmaxf(a.x + b.x, 0.f);
        z1[4 * i + 1] = fmaxf(a.y + b.y, 0.f);
        z1[4 * i + 2] = fmaxf(a.z + b.z, 0.f);
        z1[4 * i + 3] = fmaxf(a.w + b.w, 0.f);
    }
    float o = 0.f;
    for (int c = 0; c < DD; c++) {
        const float* w = dW2 + c * DD;
        float a0 = 0.f, a1 = 0.f, a2 = 0.f, a3 = 0.f;
#pragma unroll
        for (int k = 0; k < DD; k += 4) {
            a0 += z1[k] * w[k];
            a1 += z1[k + 1] * w[k + 1];
            a2 += z1[k + 2] * w[k + 2];
            a3 += z1[k + 3] * w[k + 3];
        }
        float z2 = fmaxf((a0 + a1) + (a2 + a3) + db2[c], 0.f);
        o += z2 * dW3[c];
    }
    out[q] = o + db3[0];
}

extern "C" void kernel_launch(void* const* d_in, const int* in_sizes, int n_in,
                              void* d_out, int out_size, void* d_ws, size_t ws_size,
                              hipStream_t stream) {
    const float* x_user = (const float*)d_in[0];
    const float* x_rest = (const float*)d_in[1];
    const float* Wl     = (const float*)d_in[2];   // [3,2,64,64]
    const float* Wr     = (const float*)d_in[3];
    const float* bl     = (const float*)d_in[4];   // [3,2,64]
    const float* dW1    = (const float*)d_in[5];   // [64,128]
    const float* db1    = (const float*)d_in[6];
    const float* dW2    = (const float*)d_in[7];   // [64,64]
    const float* db2    = (const float*)d_in[8];
    const float* dW3    = (const float*)d_in[9];   // [1,64]
    const float* db3    = (const float*)d_in[10];
    const int* ur_src   = (const int*)d_in[11];
    const int* ur_dst   = (const int*)d_in[12];
    const int* ru_src   = (const int*)d_in[13];
    const int* ru_dst   = (const int*)d_in[14];
    const int* el_row   = (const int*)d_in[15];
    const int* el_col   = (const int*)d_in[16];
    float* out = (float*)d_out;

    char* w = (char*)d_ws;
    size_t off = 0;
    auto alloc = [&](size_t bytes) -> void* {
        void* p = (void*)(w + off);
        off += (bytes + 255) & ~(size_t)255;
        return p;
    };
    float* hu0  = (float*)alloc((size_t)NU * DD * 4);
    float* hu1  = (float*)alloc((size_t)NU * DD * 4);   // also reused for P_u
    float* hr0  = (float*)alloc((size_t)NR * DD * 4);
    float* hr1  = (float*)alloc((size_t)NR * DD * 4);   // also reused for P_r
    float* mean = (float*)alloc((size_t)NU * DD * 4);   // shared by both sides
    int* csr_u  = (int*)alloc((size_t)NE * 4);
    int* csr_r  = (int*)alloc((size_t)NE * 4);
    int* rs_u   = (int*)alloc((size_t)(NU + 1) * 4);
    int* rs_r   = (int*)alloc((size_t)(NR + 1) * 4);
    int* cnt_u  = (int*)alloc((size_t)NU * 4);          // histogram, then cursor
    int* cnt_r  = (int*)alloc((size_t)NR * 4);
    int* bsum_u = (int*)alloc(256 * 4);
    int* bsum_r = (int*)alloc(256 * 4);

    const int nb_u = (NU + SCAN_ITEMS - 1) / SCAN_ITEMS;  // 196
    const int nb_r = (NR + SCAN_ITEMS - 1) / SCAN_ITEMS;  // 49
    const int egrid = (NE + 255) / 256;

    // ---- build CSR for both edge lists (once per call) ----
    hipMemsetAsync(cnt_u, 0, (size_t)NU * 4, stream);
    hipMemsetAsync(cnt_r, 0, (size_t)NR * 4, stream);
    count_int_kernel<<<egrid, 256, 0, stream>>>(ru_dst, cnt_u, NE);
    count_int_kernel<<<egrid, 256, 0, stream>>>(ur_dst, cnt_r, NE);
    scan_reduce_kernel<<<nb_u, 256, 0, stream>>>(cnt_u, bsum_u, NU);
    scan_bsum_kernel<<<1, 256, 0, stream>>>(bsum_u, nb_u);
    scan_write_kernel<<<nb_u, 256, 0, stream>>>(cnt_u, bsum_u, rs_u, NU, NE);
    scan_reduce_kernel<<<nb_r, 256, 0, stream>>>(cnt_r, bsum_r, NR);
    scan_bsum_kernel<<<1, 256, 0, stream>>>(bsum_r, nb_r);
    scan_write_kernel<<<nb_r, 256, 0, stream>>>(cnt_r, bsum_r, rs_r, NR, NE);
    hipMemsetAsync(cnt_u, 0, (size_t)NU * 4, stream);
    hipMemsetAsync(cnt_r, 0, (size_t)NR * 4, stream);
    fill_csr_kernel<<<egrid, 256, 0, stream>>>(ru_src, ru_dst, rs_u, cnt_u, csr_u, NE);
    fill_csr_kernel<<<egrid, 256, 0, stream>>>(ur_src, ur_dst, rs_r, cnt_r, csr_r, NE);

    // ---- 3 SAGE layers ----
    const float* cu = x_user;
    const float* cr = x_rest;
    float* nu_[3] = {hu0, hu1, hu0};
    float* nr_[3] = {hr0, hr1, hr0};

    for (int l = 0; l < 3; l++) {
        const float* Wl_r = Wl + (size_t)(l * 2 + 0) * DD * DD;
        const float* Wr_r = Wr + (size_t)(l * 2 + 0) * DD * DD;
        const float* bl_r = bl + (size_t)(l * 2 + 0) * DD;
        const float* Wl_u = Wl + (size_t)(l * 2 + 1) * DD * DD;
        const float* Wr_u = Wr + (size_t)(l * 2 + 1) * DD * DD;
        const float* bl_u = bl + (size_t)(l * 2 + 1) * DD;
        int relu = (l < 2) ? 1 : 0;

        // restaurant side: mean over user rows (ur edges), then linear
        gather_mean_kernel<<<(NR + 3) / 4, 256, 0, stream>>>(cu, csr_r, rs_r, mean, NR);
        sage_linear_kernel<<<(NR + 255) / 256, 256, 0, stream>>>(mean, cr, Wl_r, Wr_r, bl_r, nr_[l], NR, relu);
        // user side: mean over restaurant rows (ru edges), then linear
        gather_mean_kernel<<<(NU + 3) / 4, 256, 0, stream>>>(cr, csr_u, rs_u, mean, NU);
        sage_linear_kernel<<<(NU + 255) / 256, 256, 0, stream>>>(mean, cu, Wl_u, Wr_u, bl_u, nu_[l], NU, relu);

        cu = nu_[l];
        cr = nr_[l];
    }
    // final: cu == hu0, cr == hr0; hu1/hr1 are free -> hold P_u/P_r
    float* P_u = hu1;
    float* P_r = hr1;
    precompute_kernel<<<(NU + 255) / 256, 256, 0, stream>>>(cu, dW1, db1, P_u, NU, 0, 1);
    precompute_kernel<<<(NR + 255) / 256, 256, 0, stream>>>(cr, dW1, db1, P_r, NR, DD, 0);

    decoder_kernel<<<(NQ + 255) / 256, 256, 0, stream>>>(P_u, P_r, el_row, el_col,
                                                         dW2, db2, dW3, db3, out);
}

// Round 3
// 1836.468 us; speedup vs baseline: 4.1873x; 2.3241x over previous
//
#include <hip/hip_runtime.h>

#define NU 200000
#define NR 50000
#define DD 64
#define NE 2000000
#define NQ 500000
#define SCAN_ITEMS 1024

// -------------------- degree count (int) --------------------
__global__ void count_int_kernel(const int* __restrict__ dst, int* __restrict__ cnt, int n) {
    int i = blockIdx.x * blockDim.x + threadIdx.x;
    if (i < n) atomicAdd(&cnt[dst[i]], 1);
}

// -------------------- scan: per-block reduce --------------------
__global__ void scan_reduce_kernel(const int* __restrict__ cnt, int* __restrict__ bsum, int n) {
    __shared__ int s[256];
    int base = blockIdx.x * SCAN_ITEMS;
    int t = 0;
    for (int i = threadIdx.x; i < SCAN_ITEMS; i += 256) {
        int g = base + i;
        t += (g < n) ? cnt[g] : 0;
    }
    s[threadIdx.x] = t;
    __syncthreads();
    for (int off = 128; off > 0; off >>= 1) {
        if (threadIdx.x < off) s[threadIdx.x] += s[threadIdx.x + off];
        __syncthreads();
    }
    if (threadIdx.x == 0) bsum[blockIdx.x] = s[0];
}

// -------------------- scan: single-block exclusive scan of block sums ------
__global__ void scan_bsum_kernel(int* __restrict__ bsum, int nb) {
    __shared__ int a[256], b[256];
    int tid = threadIdx.x;
    a[tid] = (tid < nb) ? bsum[tid] : 0;
    __syncthreads();
    int* cur = a; int* alt = b;
    for (int off = 1; off < 256; off <<= 1) {
        int t = cur[tid];
        if (tid >= off) t += cur[tid - off];
        alt[tid] = t;
        __syncthreads();
        int* tmp = cur; cur = alt; alt = tmp;
    }
    int excl = (tid == 0) ? 0 : cur[tid - 1];
    if (tid < nb) bsum[tid] = excl;
}

// -------------------- scan: write exclusive row starts --------------------
__global__ void scan_write_kernel(const int* __restrict__ cnt, const int* __restrict__ bsum,
                                  int* __restrict__ rs, int n, int total) {
    __shared__ int sa[256], sb[256];
    int tid = threadIdx.x;
    int base = blockIdx.x * SCAN_ITEMS;
    int loc[4];
    int t = 0;
#pragma unroll
    for (int i = 0; i < 4; i++) {
        int g = base + tid * 4 + i;
        int v = (g < n) ? cnt[g] : 0;
        loc[i] = t;
        t += v;
    }
    sa[tid] = t;
    __syncthreads();
    int* cur = sa; int* alt = sb;
    for (int off = 1; off < 256; off <<= 1) {
        int x = cur[tid];
        if (tid >= off) x += cur[tid - off];
        alt[tid] = x;
        __syncthreads();
        int* tmp = cur; cur = alt; alt = tmp;
    }
    int texcl = cur[tid] - t;  // exclusive prefix of this thread
    int off0 = bsum[blockIdx.x] + texcl;
#pragma unroll
    for (int i = 0; i < 4; i++) {
        int g = base + tid * 4 + i;
        if (g < n) rs[g] = off0 + loc[i];
    }
    if (blockIdx.x == 0 && tid == 0) rs[n] = total;
}

// -------------------- CSR fill --------------------
__global__ void fill_csr_kernel(const int* __restrict__ src, const int* __restrict__ dst,
                                const int* __restrict__ rs, int* __restrict__ cursor,
                                int* __restrict__ csr, int n) {
    int e = blockIdx.x * blockDim.x + threadIdx.x;
    if (e < n) {
        int d = dst[e];
        int pos = atomicAdd(&cursor[d], 1);
        csr[rs[d] + pos] = src[e];
    }
}

// -------------------- gather mean: wave per dst row --------------------
__global__ __launch_bounds__(256)
void gather_mean_kernel(const float* __restrict__ h, const int* __restrict__ csr,
                        const int* __restrict__ rs, float* __restrict__ mean, int nrows) {
    int lane = threadIdx.x & 63;
    int wave = blockIdx.x * 4 + (threadIdx.x >> 6);
    if (wave >= nrows) return;
    int r = wave;
    int s = rs[r], e = rs[r + 1];
    float a0 = 0.f, a1 = 0.f, a2 = 0.f, a3 = 0.f;
    for (int j = s; j < e; j += 64) {
        int rem = e - j;
        int nch = rem < 64 ? rem : 64;
        int li = lane < nch ? lane : nch - 1;
        int idx = csr[j + li];  // clamped: all lanes hold a valid id
        for (int kk = 0; kk < nch; kk += 4) {
            int i0 = __shfl(idx, kk);
            int i1 = __shfl(idx, kk + 1);
            int i2 = __shfl(idx, kk + 2);
            int i3 = __shfl(idx, kk + 3);
            float v0 = h[i0 * DD + lane];
            float v1 = h[i1 * DD + lane];
            float v2 = h[i2 * DD + lane];
            float v3 = h[i3 * DD + lane];
            a0 += v0;                              // kk < nch always
            a1 += (kk + 1 < nch) ? v1 : 0.f;
            a2 += (kk + 2 < nch) ? v2 : 0.f;
            a3 += (kk + 3 < nch) ? v3 : 0.f;
        }
    }
    float acc = (a0 + a1) + (a2 + a3);
    float inv = 1.0f / fmaxf((float)(e - s), 1.0f);
    mean[r * DD + lane] = acc * inv;
}

// -------------------- SAGE linear: thread per row, acc-resident ---------
// out[r][c] = bias[c] + sum_k mean[r][k]*Wl[c][k] + sum_k h[r][k]*Wr[c][k]
// 64 accumulators live in VGPRs; K streamed in chunks of 8 -> no spill.
__global__ __launch_bounds__(256)
void sage_linear_kernel(const float* __restrict__ mean, const float* __restrict__ h,
                        const float* __restrict__ Wl, const float* __restrict__ Wr,
                        const float* __restrict__ bias,
                        float* __restrict__ out, int n, int do_relu) {
    int r = blockIdx.x * 256 + threadIdx.x;
    if (r >= n) return;
    float acc[DD];
#pragma unroll
    for (int c = 0; c < DD; c++) acc[c] = bias[c];   // wave-uniform scalar loads
    const float* mrow = mean + (size_t)r * DD;
    const float* xrow = h + (size_t)r * DD;
#pragma unroll 1
    for (int kc = 0; kc < DD; kc += 8) {
        float4 a0 = *(const float4*)(mrow + kc);
        float4 a1 = *(const float4*)(mrow + kc + 4);
        float4 b0 = *(const float4*)(xrow + kc);
        float4 b1 = *(const float4*)(xrow + kc + 4);
        float m[8] = {a0.x, a0.y, a0.z, a0.w, a1.x, a1.y, a1.z, a1.w};
        float x[8] = {b0.x, b0.y, b0.z, b0.w, b1.x, b1.y, b1.z, b1.w};
#pragma unroll
        for (int c = 0; c < DD; c++) {
            const float* wl = Wl + c * DD + kc;
            const float* wr = Wr + c * DD + kc;
            float s0 = 0.f, s1 = 0.f;
#pragma unroll
            for (int j = 0; j < 8; j++) {
                s0 += m[j] * wl[j];
                s1 += x[j] * wr[j];
            }
            acc[c] += s0 + s1;
        }
    }
    float4* o = (float4*)(out + (size_t)r * DD);
#pragma unroll
    for (int i = 0; i < 16; i++) {
        float4 v;
        v.x = acc[4 * i];     v.y = acc[4 * i + 1];
        v.z = acc[4 * i + 2]; v.w = acc[4 * i + 3];
        if (do_relu) {
            v.x = fmaxf(v.x, 0.f); v.y = fmaxf(v.y, 0.f);
            v.z = fmaxf(v.z, 0.f); v.w = fmaxf(v.w, 0.f);
        }
        o[i] = v;
    }
}

// -------------------- decoder layer-1 precompute ---------------------------
// P[r][c] = (add_bias ? db1[c] : 0) + sum_k h[r][k] * dW1[c*128 + koff + k]
__global__ __launch_bounds__(256)
void precompute_kernel(const float* __restrict__ h, const float* __restrict__ dW1,
                       const float* __restrict__ db1, float* __restrict__ P,
                       int n, int koff, int add_bias) {
    int r = blockIdx.x * 256 + threadIdx.x;
    if (r >= n) return;
    float acc[DD];
#pragma unroll
    for (int c = 0; c < DD; c++) acc[c] = add_bias ? db1[c] : 0.f;
    const float* xrow = h + (size_t)r * DD;
#pragma unroll 1
    for (int kc = 0; kc < DD; kc += 8) {
        float4 b0 = *(const float4*)(xrow + kc);
        float4 b1 = *(const float4*)(xrow + kc + 4);
        float x[8] = {b0.x, b0.y, b0.z, b0.w, b1.x, b1.y, b1.z, b1.w};
#pragma unroll
        for (int c = 0; c < DD; c++) {
            const float* w = dW1 + c * 2 * DD + koff + kc;
            float s = 0.f;
#pragma unroll
            for (int j = 0; j < 8; j++) s += x[j] * w[j];
            acc[c] += s;
        }
    }
    float4* o = (float4*)(P + (size_t)r * DD);
#pragma unroll
    for (int i = 0; i < 16; i++) {
        float4 v;
        v.x = acc[4 * i];     v.y = acc[4 * i + 1];
        v.z = acc[4 * i + 2]; v.w = acc[4 * i + 3];
        o[i] = v;
    }
}

// -------------------- fused decoder: thread per query ----------------------
__global__ __launch_bounds__(256)
void decoder_kernel(const float* __restrict__ Pu, const float* __restrict__ Pr,
                    const int* __restrict__ el_row, const int* __restrict__ el_col,
                    const float* __restrict__ dW2, const float* __restrict__ db2,
                    const float* __restrict__ dW3, const float* __restrict__ db3,
                    float* __restrict__ out) {
    int q = blockIdx.x * 256 + threadIdx.x;
    if (q >= NQ) return;
    int row = el_row[q], col = el_col[q];
    const float4* pu = (const float4*)(Pu + (size_t)row * DD);
    const float4* pr = (const float4*)(Pr + (size_t)col * DD);
    float z1[DD];
#pragma unroll
    for (int i = 0; i < 16; i++) {
        float4 a = pu[i];
        float4 b = pr[i];
        z1[4 * i]     = fmaxf(a.x + b.x, 0.f);
        z1[4 * i + 1] = fmaxf(a.y + b.y, 0.f);
        z1[4 * i + 2] = fmaxf(a.z + b.z, 0.f);
        z1[4 * i + 3] = fmaxf(a.w + b.w, 0.f);
    }
    float o = 0.f;
#pragma unroll 1
    for (int c = 0; c < DD; c++) {
        const float* w = dW2 + c * DD;
        float a0 = 0.f, a1 = 0.f, a2 = 0.f, a3 = 0.f;
#pragma unroll
        for (int k = 0; k < DD; k += 4) {
            a0 += z1[k] * w[k];
            a1 += z1[k + 1] * w[k + 1];
            a2 += z1[k + 2] * w[k + 2];
            a3 += z1[k + 3] * w[k + 3];
        }
        float z2 = fmaxf((a0 + a1) + (a2 + a3) + db2[c], 0.f);
        o += z2 * dW3[c];
    }
    out[q] = o + db3[0];
}

extern "C" void kernel_launch(void* const* d_in, const int* in_sizes, int n_in,
                              void* d_out, int out_size, void* d_ws, size_t ws_size,
                              hipStream_t stream) {
    const float* x_user = (const float*)d_in[0];
    const float* x_rest = (const float*)d_in[1];
    const float* Wl     = (const float*)d_in[2];   // [3,2,64,64]
    const float* Wr     = (const float*)d_in[3];
    const float* bl     = (const float*)d_in[4];   // [3,2,64]
    const float* dW1    = (const float*)d_in[5];   // [64,128]
    const float* db1    = (const float*)d_in[6];
    const float* dW2    = (const float*)d_in[7];   // [64,64]
    const float* db2    = (const float*)d_in[8];
    const float* dW3    = (const float*)d_in[9];   // [1,64]
    const float* db3    = (const float*)d_in[10];
    const int* ur_src   = (const int*)d_in[11];
    const int* ur_dst   = (const int*)d_in[12];
    const int* ru_src   = (const int*)d_in[13];
    const int* ru_dst   = (const int*)d_in[14];
    const int* el_row   = (const int*)d_in[15];
    const int* el_col   = (const int*)d_in[16];
    float* out = (float*)d_out;

    char* w = (char*)d_ws;
    size_t off = 0;
    auto alloc = [&](size_t bytes) -> void* {
        void* p = (void*)(w + off);
        off += (bytes + 255) & ~(size_t)255;
        return p;
    };
    float* hu0  = (float*)alloc((size_t)NU * DD * 4);
    float* hu1  = (float*)alloc((size_t)NU * DD * 4);   // also reused for P_u
    float* hr0  = (float*)alloc((size_t)NR * DD * 4);
    float* hr1  = (float*)alloc((size_t)NR * DD * 4);   // also reused for P_r
    float* mean = (float*)alloc((size_t)NU * DD * 4);   // shared by both sides
    int* csr_u  = (int*)alloc((size_t)NE * 4);
    int* csr_r  = (int*)alloc((size_t)NE * 4);
    int* rs_u   = (int*)alloc((size_t)(NU + 1) * 4);
    int* rs_r   = (int*)alloc((size_t)(NR + 1) * 4);
    int* cnt_u  = (int*)alloc((size_t)NU * 4);          // histogram, then cursor
    int* cnt_r  = (int*)alloc((size_t)NR * 4);
    int* bsum_u = (int*)alloc(256 * 4);
    int* bsum_r = (int*)alloc(256 * 4);

    const int nb_u = (NU + SCAN_ITEMS - 1) / SCAN_ITEMS;  // 196
    const int nb_r = (NR + SCAN_ITEMS - 1) / SCAN_ITEMS;  // 49
    const int egrid = (NE + 255) / 256;

    // ---- build CSR for both edge lists (once per call) ----
    hipMemsetAsync(cnt_u, 0, (size_t)NU * 4, stream);
    hipMemsetAsync(cnt_r, 0, (size_t)NR * 4, stream);
    count_int_kernel<<<egrid, 256, 0, stream>>>(ru_dst, cnt_u, NE);
    count_int_kernel<<<egrid, 256, 0, stream>>>(ur_dst, cnt_r, NE);
    scan_reduce_kernel<<<nb_u, 256, 0, stream>>>(cnt_u, bsum_u, NU);
    scan_bsum_kernel<<<1, 256, 0, stream>>>(bsum_u, nb_u);
    scan_write_kernel<<<nb_u, 256, 0, stream>>>(cnt_u, bsum_u, rs_u, NU, NE);
    scan_reduce_kernel<<<nb_r, 256, 0, stream>>>(cnt_r, bsum_r, NR);
    scan_bsum_kernel<<<1, 256, 0, stream>>>(bsum_r, nb_r);
    scan_write_kernel<<<nb_r, 256, 0, stream>>>(cnt_r, bsum_r, rs_r, NR, NE);
    hipMemsetAsync(cnt_u, 0, (size_t)NU * 4, stream);
    hipMemsetAsync(cnt_r, 0, (size_t)NR * 4, stream);
    fill_csr_kernel<<<egrid, 256, 0, stream>>>(ru_src, ru_dst, rs_u, cnt_u, csr_u, NE);
    fill_csr_kernel<<<egrid, 256, 0, stream>>>(ur_src, ur_dst, rs_r, cnt_r, csr_r, NE);

    // ---- 3 SAGE layers ----
    const float* cu = x_user;
    const float* cr = x_rest;
    float* nu_[3] = {hu0, hu1, hu0};
    float* nr_[3] = {hr0, hr1, hr0};

    for (int l = 0; l < 3; l++) {
        const float* Wl_r = Wl + (size_t)(l * 2 + 0) * DD * DD;
        const float* Wr_r = Wr + (size_t)(l * 2 + 0) * DD * DD;
        const float* bl_r = bl + (size_t)(l * 2 + 0) * DD;
        const float* Wl_u = Wl + (size_t)(l * 2 + 1) * DD * DD;
        const float* Wr_u = Wr + (size_t)(l * 2 + 1) * DD * DD;
        const float* bl_u = bl + (size_t)(l * 2 + 1) * DD;
        int relu = (l < 2) ? 1 : 0;

        // restaurant side: mean over user rows (ur edges), then linear
        gather_mean_kernel<<<(NR + 3) / 4, 256, 0, stream>>>(cu, csr_r, rs_r, mean, NR);
        sage_linear_kernel<<<(NR + 255) / 256, 256, 0, stream>>>(mean, cr, Wl_r, Wr_r, bl_r, nr_[l], NR, relu);
        // user side: mean over restaurant rows (ru edges), then linear
        gather_mean_kernel<<<(NU + 3) / 4, 256, 0, stream>>>(cr, csr_u, rs_u, mean, NU);
        sage_linear_kernel<<<(NU + 255) / 256, 256, 0, stream>>>(mean, cu, Wl_u, Wr_u, bl_u, nu_[l], NU, relu);

        cu = nu_[l];
        cr = nr_[l];
    }
    // final: cu == hu0, cr == hr0; hu1/hr1 are free -> hold P_u/P_r
    float* P_u = hu1;
    float* P_r = hr1;
    precompute_kernel<<<(NU + 255) / 256, 256, 0, stream>>>(cu, dW1, db1, P_u, NU, 0, 1);
    precompute_kernel<<<(NR + 255) / 256, 256, 0, stream>>>(cr, dW1, db1, P_r, NR, DD, 0);

    decoder_kernel<<<(NQ + 255) / 256, 256, 0, stream>>>(P_u, P_r, el_row, el_col,
                                                         dW2, db2, dW3, db3, out);
}

// Round 4
// 1827.804 us; speedup vs baseline: 4.2072x; 1.0047x over previous
//
#include <hip/hip_runtime.h>

#define NU 200000
#define NR 50000
#define DD 64
#define NE 2000000
#define NQ 500000
#define SCAN_ITEMS 1024

// -------------------- degree count (int) --------------------
__global__ void count_int_kernel(const int* __restrict__ dst, int* __restrict__ cnt, int n) {
    int i = blockIdx.x * blockDim.x + threadIdx.x;
    if (i < n) atomicAdd(&cnt[dst[i]], 1);
}

// -------------------- scan: per-block reduce --------------------
__global__ void scan_reduce_kernel(const int* __restrict__ cnt, int* __restrict__ bsum, int n) {
    __shared__ int s[256];
    int base = blockIdx.x * SCAN_ITEMS;
    int t = 0;
    for (int i = threadIdx.x; i < SCAN_ITEMS; i += 256) {
        int g = base + i;
        t += (g < n) ? cnt[g] : 0;
    }
    s[threadIdx.x] = t;
    __syncthreads();
    for (int off = 128; off > 0; off >>= 1) {
        if (threadIdx.x < off) s[threadIdx.x] += s[threadIdx.x + off];
        __syncthreads();
    }
    if (threadIdx.x == 0) bsum[blockIdx.x] = s[0];
}

// -------------------- scan: single-block exclusive scan of block sums ------
__global__ void scan_bsum_kernel(int* __restrict__ bsum, int nb) {
    __shared__ int a[256], b[256];
    int tid = threadIdx.x;
    a[tid] = (tid < nb) ? bsum[tid] : 0;
    __syncthreads();
    int* cur = a; int* alt = b;
    for (int off = 1; off < 256; off <<= 1) {
        int t = cur[tid];
        if (tid >= off) t += cur[tid - off];
        alt[tid] = t;
        __syncthreads();
        int* tmp = cur; cur = alt; alt = tmp;
    }
    int excl = (tid == 0) ? 0 : cur[tid - 1];
    if (tid < nb) bsum[tid] = excl;
}

// -------------------- scan: write exclusive row starts --------------------
__global__ void scan_write_kernel(const int* __restrict__ cnt, const int* __restrict__ bsum,
                                  int* __restrict__ rs, int n, int total) {
    __shared__ int sa[256], sb[256];
    int tid = threadIdx.x;
    int base = blockIdx.x * SCAN_ITEMS;
    int loc[4];
    int t = 0;
#pragma unroll
    for (int i = 0; i < 4; i++) {
        int g = base + tid * 4 + i;
        int v = (g < n) ? cnt[g] : 0;
        loc[i] = t;
        t += v;
    }
    sa[tid] = t;
    __syncthreads();
    int* cur = sa; int* alt = sb;
    for (int off = 1; off < 256; off <<= 1) {
        int x = cur[tid];
        if (tid >= off) x += cur[tid - off];
        alt[tid] = x;
        __syncthreads();
        int* tmp = cur; cur = alt; alt = tmp;
    }
    int texcl = cur[tid] - t;  // exclusive prefix of this thread
    int off0 = bsum[blockIdx.x] + texcl;
#pragma unroll
    for (int i = 0; i < 4; i++) {
        int g = base + tid * 4 + i;
        if (g < n) rs[g] = off0 + loc[i];
    }
    if (blockIdx.x == 0 && tid == 0) rs[n] = total;
}

// -------------------- CSR fill --------------------
__global__ void fill_csr_kernel(const int* __restrict__ src, const int* __restrict__ dst,
                                const int* __restrict__ rs, int* __restrict__ cursor,
                                int* __restrict__ csr, int n) {
    int e = blockIdx.x * blockDim.x + threadIdx.x;
    if (e < n) {
        int d = dst[e];
        int pos = atomicAdd(&cursor[d], 1);
        csr[rs[d] + pos] = src[e];
    }
}

// -------------------- gather mean: wave per dst row --------------------
__global__ __launch_bounds__(256)
void gather_mean_kernel(const float* __restrict__ h, const int* __restrict__ csr,
                        const int* __restrict__ rs, float* __restrict__ mean, int nrows) {
    int lane = threadIdx.x & 63;
    int wave = blockIdx.x * 4 + (threadIdx.x >> 6);
    if (wave >= nrows) return;
    int r = wave;
    int s = rs[r], e = rs[r + 1];
    float a0 = 0.f, a1 = 0.f, a2 = 0.f, a3 = 0.f;
    for (int j = s; j < e; j += 64) {
        int rem = e - j;
        int nch = rem < 64 ? rem : 64;
        int li = lane < nch ? lane : nch - 1;
        int idx = csr[j + li];  // clamped: all lanes hold a valid id
        for (int kk = 0; kk < nch; kk += 4) {
            int i0 = __shfl(idx, kk);
            int i1 = __shfl(idx, kk + 1);
            int i2 = __shfl(idx, kk + 2);
            int i3 = __shfl(idx, kk + 3);
            float v0 = h[i0 * DD + lane];
            float v1 = h[i1 * DD + lane];
            float v2 = h[i2 * DD + lane];
            float v3 = h[i3 * DD + lane];
            a0 += v0;                              // kk < nch always
            a1 += (kk + 1 < nch) ? v1 : 0.f;
            a2 += (kk + 2 < nch) ? v2 : 0.f;
            a3 += (kk + 3 < nch) ? v3 : 0.f;
        }
    }
    float acc = (a0 + a1) + (a2 + a3);
    float inv = 1.0f / fmaxf((float)(e - s), 1.0f);
    mean[r * DD + lane] = acc * inv;
}

// -------------------- SAGE linear: thread per row, acc-resident ---------
// out[r][c] = bias[c] + sum_k mean[r][k]*Wl[c][k] + sum_k h[r][k]*Wr[c][k]
// 64 accumulators in VGPRs; (256,2) launch bounds -> VGPR cap 256, no spill.
__global__ __launch_bounds__(256, 2)
void sage_linear_kernel(const float* __restrict__ mean, const float* __restrict__ h,
                        const float* __restrict__ Wl, const float* __restrict__ Wr,
                        const float* __restrict__ bias,
                        float* __restrict__ out, int n, int do_relu) {
    int r = blockIdx.x * 256 + threadIdx.x;
    if (r >= n) return;
    float acc[DD];
#pragma unroll
    for (int c = 0; c < DD; c++) acc[c] = bias[c];   // wave-uniform scalar loads
    const float* mrow = mean + (size_t)r * DD;
    const float* xrow = h + (size_t)r * DD;
#pragma unroll 1
    for (int kc = 0; kc < DD; kc += 8) {
        float4 a0 = *(const float4*)(mrow + kc);
        float4 a1 = *(const float4*)(mrow + kc + 4);
        float4 b0 = *(const float4*)(xrow + kc);
        float4 b1 = *(const float4*)(xrow + kc + 4);
        float m[8] = {a0.x, a0.y, a0.z, a0.w, a1.x, a1.y, a1.z, a1.w};
        float x[8] = {b0.x, b0.y, b0.z, b0.w, b1.x, b1.y, b1.z, b1.w};
#pragma unroll
        for (int c = 0; c < DD; c++) {
            const float* wl = Wl + c * DD + kc;
            const float* wr = Wr + c * DD + kc;
            float s0 = 0.f, s1 = 0.f;
#pragma unroll
            for (int j = 0; j < 8; j++) {
                s0 += m[j] * wl[j];
                s1 += x[j] * wr[j];
            }
            acc[c] += s0 + s1;
        }
    }
    float4* o = (float4*)(out + (size_t)r * DD);
#pragma unroll
    for (int i = 0; i < 16; i++) {
        float4 v;
        v.x = acc[4 * i];     v.y = acc[4 * i + 1];
        v.z = acc[4 * i + 2]; v.w = acc[4 * i + 3];
        if (do_relu) {
            v.x = fmaxf(v.x, 0.f); v.y = fmaxf(v.y, 0.f);
            v.z = fmaxf(v.z, 0.f); v.w = fmaxf(v.w, 0.f);
        }
        o[i] = v;
    }
}

// -------------------- decoder layer-1 precompute ---------------------------
// P[r][c] = (add_bias ? db1[c] : 0) + sum_k h[r][k] * dW1[c*128 + koff + k]
__global__ __launch_bounds__(256, 2)
void precompute_kernel(const float* __restrict__ h, const float* __restrict__ dW1,
                       const float* __restrict__ db1, float* __restrict__ P,
                       int n, int koff, int add_bias) {
    int r = blockIdx.x * 256 + threadIdx.x;
    if (r >= n) return;
    float acc[DD];
#pragma unroll
    for (int c = 0; c < DD; c++) acc[c] = add_bias ? db1[c] : 0.f;
    const float* xrow = h + (size_t)r * DD;
#pragma unroll 1
    for (int kc = 0; kc < DD; kc += 8) {
        float4 b0 = *(const float4*)(xrow + kc);
        float4 b1 = *(const float4*)(xrow + kc + 4);
        float x[8] = {b0.x, b0.y, b0.z, b0.w, b1.x, b1.y, b1.z, b1.w};
#pragma unroll
        for (int c = 0; c < DD; c++) {
            const float* w = dW1 + c * 2 * DD + koff + kc;
            float s = 0.f;
#pragma unroll
            for (int j = 0; j < 8; j++) s += x[j] * w[j];
            acc[c] += s;
        }
    }
    float4* o = (float4*)(P + (size_t)r * DD);
#pragma unroll
    for (int i = 0; i < 16; i++) {
        float4 v;
        v.x = acc[4 * i];     v.y = acc[4 * i + 1];
        v.z = acc[4 * i + 2]; v.w = acc[4 * i + 3];
        o[i] = v;
    }
}

// -------------------- fused decoder: thread per query ----------------------
__global__ __launch_bounds__(256, 2)
void decoder_kernel(const float* __restrict__ Pu, const float* __restrict__ Pr,
                    const int* __restrict__ el_row, const int* __restrict__ el_col,
                    const float* __restrict__ dW2, const float* __restrict__ db2,
                    const float* __restrict__ dW3, const float* __restrict__ db3,
                    float* __restrict__ out) {
    int q = blockIdx.x * 256 + threadIdx.x;
    if (q >= NQ) return;
    int row = el_row[q], col = el_col[q];
    const float4* pu = (const float4*)(Pu + (size_t)row * DD);
    const float4* pr = (const float4*)(Pr + (size_t)col * DD);
    float z1[DD];
#pragma unroll
    for (int i = 0; i < 16; i++) {
        float4 a = pu[i];
        float4 b = pr[i];
        z1[4 * i]     = fmaxf(a.x + b.x, 0.f);
        z1[4 * i + 1] = fmaxf(a.y + b.y, 0.f);
        z1[4 * i + 2] = fmaxf(a.z + b.z, 0.f);
        z1[4 * i + 3] = fmaxf(a.w + b.w, 0.f);
    }
    float o = 0.f;
#pragma unroll 1
    for (int c = 0; c < DD; c++) {
        const float* w = dW2 + c * DD;
        float a0 = 0.f, a1 = 0.f, a2 = 0.f, a3 = 0.f;
#pragma unroll
        for (int k = 0; k < DD; k += 4) {
            a0 += z1[k] * w[k];
            a1 += z1[k + 1] * w[k + 1];
            a2 += z1[k + 2] * w[k + 2];
            a3 += z1[k + 3] * w[k + 3];
        }
        float z2 = fmaxf((a0 + a1) + (a2 + a3) + db2[c], 0.f);
        o += z2 * dW3[c];
    }
    out[q] = o + db3[0];
}

extern "C" void kernel_launch(void* const* d_in, const int* in_sizes, int n_in,
                              void* d_out, int out_size, void* d_ws, size_t ws_size,
                              hipStream_t stream) {
    const float* x_user = (const float*)d_in[0];
    const float* x_rest = (const float*)d_in[1];
    const float* Wl     = (const float*)d_in[2];   // [3,2,64,64]
    const float* Wr     = (const float*)d_in[3];
    const float* bl     = (const float*)d_in[4];   // [3,2,64]
    const float* dW1    = (const float*)d_in[5];   // [64,128]
    const float* db1    = (const float*)d_in[6];
    const float* dW2    = (const float*)d_in[7];   // [64,64]
    const float* db2    = (const float*)d_in[8];
    const float* dW3    = (const float*)d_in[9];   // [1,64]
    const float* db3    = (const float*)d_in[10];
    const int* ur_src   = (const int*)d_in[11];
    const int* ur_dst   = (const int*)d_in[12];
    const int* ru_src   = (const int*)d_in[13];
    const int* ru_dst   = (const int*)d_in[14];
    const int* el_row   = (const int*)d_in[15];
    const int* el_col   = (const int*)d_in[16];
    float* out = (float*)d_out;

    char* w = (char*)d_ws;
    size_t off = 0;
    auto alloc = [&](size_t bytes) -> void* {
        void* p = (void*)(w + off);
        off += (bytes + 255) & ~(size_t)255;
        return p;
    };
    float* hu0  = (float*)alloc((size_t)NU * DD * 4);
    float* hu1  = (float*)alloc((size_t)NU * DD * 4);   // also reused for P_u
    float* hr0  = (float*)alloc((size_t)NR * DD * 4);
    float* hr1  = (float*)alloc((size_t)NR * DD * 4);   // also reused for P_r
    float* mean = (float*)alloc((size_t)NU * DD * 4);   // shared by both sides
    int* csr_u  = (int*)alloc((size_t)NE * 4);
    int* csr_r  = (int*)alloc((size_t)NE * 4);
    int* rs_u   = (int*)alloc((size_t)(NU + 1) * 4);
    int* rs_r   = (int*)alloc((size_t)(NR + 1) * 4);
    int* cnt_u  = (int*)alloc((size_t)NU * 4);          // histogram, then cursor
    int* cnt_r  = (int*)alloc((size_t)NR * 4);
    int* bsum_u = (int*)alloc(256 * 4);
    int* bsum_r = (int*)alloc(256 * 4);

    const int nb_u = (NU + SCAN_ITEMS - 1) / SCAN_ITEMS;  // 196
    const int nb_r = (NR + SCAN_ITEMS - 1) / SCAN_ITEMS;  // 49
    const int egrid = (NE + 255) / 256;

    // ---- build CSR for both edge lists (once per call) ----
    hipMemsetAsync(cnt_u, 0, (size_t)NU * 4, stream);
    hipMemsetAsync(cnt_r, 0, (size_t)NR * 4, stream);
    count_int_kernel<<<egrid, 256, 0, stream>>>(ru_dst, cnt_u, NE);
    count_int_kernel<<<egrid, 256, 0, stream>>>(ur_dst, cnt_r, NE);
    scan_reduce_kernel<<<nb_u, 256, 0, stream>>>(cnt_u, bsum_u, NU);
    scan_bsum_kernel<<<1, 256, 0, stream>>>(bsum_u, nb_u);
    scan_write_kernel<<<nb_u, 256, 0, stream>>>(cnt_u, bsum_u, rs_u, NU, NE);
    scan_reduce_kernel<<<nb_r, 256, 0, stream>>>(cnt_r, bsum_r, NR);
    scan_bsum_kernel<<<1, 256, 0, stream>>>(bsum_r, nb_r);
    scan_write_kernel<<<nb_r, 256, 0, stream>>>(cnt_r, bsum_r, rs_r, NR, NE);
    hipMemsetAsync(cnt_u, 0, (size_t)NU * 4, stream);
    hipMemsetAsync(cnt_r, 0, (size_t)NR * 4, stream);
    fill_csr_kernel<<<egrid, 256, 0, stream>>>(ru_src, ru_dst, rs_u, cnt_u, csr_u, NE);
    fill_csr_kernel<<<egrid, 256, 0, stream>>>(ur_src, ur_dst, rs_r, cnt_r, csr_r, NE);

    // ---- 3 SAGE layers ----
    const float* cu = x_user;
    const float* cr = x_rest;
    float* nu_[3] = {hu0, hu1, hu0};
    float* nr_[3] = {hr0, hr1, hr0};

    for (int l = 0; l < 3; l++) {
        const float* Wl_r = Wl + (size_t)(l * 2 + 0) * DD * DD;
        const float* Wr_r = Wr + (size_t)(l * 2 + 0) * DD * DD;
        const float* bl_r = bl + (size_t)(l * 2 + 0) * DD;
        const float* Wl_u = Wl + (size_t)(l * 2 + 1) * DD * DD;
        const float* Wr_u = Wr + (size_t)(l * 2 + 1) * DD * DD;
        const float* bl_u = bl + (size_t)(l * 2 + 1) * DD;
        int relu = (l < 2) ? 1 : 0;

        // restaurant side: mean over user rows (ur edges), then linear
        gather_mean_kernel<<<(NR + 3) / 4, 256, 0, stream>>>(cu, csr_r, rs_r, mean, NR);
        sage_linear_kernel<<<(NR + 255) / 256, 256, 0, stream>>>(mean, cr, Wl_r, Wr_r, bl_r, nr_[l], NR, relu);
        // user side: mean over restaurant rows (ru edges), then linear
        gather_mean_kernel<<<(NU + 3) / 4, 256, 0, stream>>>(cr, csr_u, rs_u, mean, NU);
        sage_linear_kernel<<<(NU + 255) / 256, 256, 0, stream>>>(mean, cu, Wl_u, Wr_u, bl_u, nu_[l], NU, relu);

        cu = nu_[l];
        cr = nr_[l];
    }
    // final: cu == hu0, cr == hr0; hu1/hr1 are free -> hold P_u/P_r
    float* P_u = hu1;
    float* P_r = hr1;
    precompute_kernel<<<(NU + 255) / 256, 256, 0, stream>>>(cu, dW1, db1, P_u, NU, 0, 1);
    precompute_kernel<<<(NR + 255) / 256, 256, 0, stream>>>(cr, dW1, db1, P_r, NR, DD, 0);

    decoder_kernel<<<(NQ + 255) / 256, 256, 0, stream>>>(P_u, P_r, el_row, el_col,
                                                         dW2, db2, dW3, db3, out);
}